// Round 28
// baseline (404.477 us; speedup 1.0000x reference)
//
#include <hip/hip_runtime.h>

// ---------------------------------------------------------------------------
// CrossAttention: out = (softmax_causal_masked((xWq)(yWkv_k)^T/8) (yWkv_v)) Wo
// B=4, S=2048, H=1024, NH=16, HD=64
// ---------------------------------------------------------------------------

#define Bv   4
#define Sv   2048
#define Hv   1024
#define NHv  16
#define HDv  64

typedef __attribute__((ext_vector_type(8))) short s16x8;
typedef __attribute__((ext_vector_type(4))) short s16x4;
typedef __attribute__((ext_vector_type(4))) float f32x4;

__device__ __forceinline__ short f2bf(float f) {   // RNE
  unsigned u = __float_as_uint(f);
  unsigned r = (u + 0x7fffu + ((u >> 16) & 1u)) >> 16;
  return (short)r;
}

#if __has_builtin(__builtin_amdgcn_exp2f)
#define EXP2(x) __builtin_amdgcn_exp2f(x)
#else
#define EXP2(x) exp2f(x)
#endif

// async global->LDS, 16B per lane (dest = wave-uniform base + lane*16)
__device__ __forceinline__ void gl_lds16(const short* g, short* l) {
  __builtin_amdgcn_global_load_lds(
      (const __attribute__((address_space(1))) unsigned int*)g,
      (__attribute__((address_space(3))) unsigned int*)l, 16, 0, 0);
}

// ---------------- fp32 -> bf16 convert (x and y in one launch) -------------
__global__ __launch_bounds__(256) void cvt2_bf16(const float* __restrict__ x,
                                                 const float* __restrict__ y,
                                                 short* __restrict__ Xb,
                                                 short* __restrict__ Yb, int nper) {
  int half = gridDim.x >> 1;
  int bid = blockIdx.x;
  const float* in = (bid < half) ? x : y;
  short* out = (bid < half) ? Xb : Yb;
  int lb = (bid < half) ? bid : bid - half;
  int i = (lb * 256 + threadIdx.x) * 4;
  if (i < nper) {
    float4 v = *(const float4*)&in[i];
    short r0 = f2bf(v.x), r1 = f2bf(v.y), r2 = f2bf(v.z), r3 = f2bf(v.w);
    unsigned long long pk = (unsigned long long)(unsigned short)r0
                          | ((unsigned long long)(unsigned short)r1 << 16)
                          | ((unsigned long long)(unsigned short)r2 << 32)
                          | ((unsigned long long)(unsigned short)r3 << 48);
    *(unsigned long long*)&out[i] = pk;
  }
}

// ---------------- all three weights: fp32 [R][C] -> bf16 [C][R] ------------
__global__ __launch_bounds__(256)
void tcvt3(const float* __restrict__ Wq, const float* __restrict__ Wkv,
           const float* __restrict__ Wo, short* __restrict__ Wt,
           short* __restrict__ Wot) {
  __shared__ float tile[32][33];
  int bx = blockIdx.x;
  const float* in;
  short* out;
  int C, cx;
  if (bx < 32)       { in = Wq;  out = Wt;                          C = 1024; cx = bx; }
  else if (bx < 96)  { in = Wkv; out = Wt + (size_t)Hv * Hv;        C = 2048; cx = bx - 32; }
  else               { in = Wo;  out = Wot;                         C = 1024; cx = bx - 96; }
  const int R = 1024;
  int tx = threadIdx.x & 31, ty = threadIdx.x >> 5;  // ty 0..7
  int c0 = cx * 32, r0 = blockIdx.y * 32;
#pragma unroll
  for (int i = 0; i < 32; i += 8)
    tile[ty + i][tx] = in[(size_t)(r0 + ty + i) * C + c0 + tx];
  __syncthreads();
#pragma unroll
  for (int i = 0; i < 32; i += 8)
    out[(size_t)(c0 + ty + i) * R + r0 + tx] = f2bf(tile[tx][ty + i]);
}

// ---------------- fused QKV projection GEMM --------------------------------
// Counted-vmcnt ping-pong (R23: 846 TF). LDS-staged epilogue.
__global__ __launch_bounds__(256)
void gemm_qkv(const short* __restrict__ Xb, const short* __restrict__ Yb,
              const short* __restrict__ Wt, const float* __restrict__ Wqb,
              const float* __restrict__ Wkvb, short* __restrict__ Qb,
              short* __restrict__ Kb, short* __restrict__ Vt) {
  __shared__ union SMem {
    struct { short A[2][128 * 64]; short B[2][128 * 64]; } g;
    short ep[128 * 136];                    // epilogue staging (pad 136)
  } sm;
  const int tid = threadIdx.x;
  const int w = tid >> 6, l = tid & 63;
  const int wr = w >> 1, wc = w & 1;
  const int m0 = blockIdx.x * 128, n0 = blockIdx.y * 128;
  const short* A = (n0 < 1024) ? Xb : Yb;
  const int sel = n0 >> 10;                 // 0=Q, 1=K, 2=V (blocks are pure)

  auto STAGE = [&](int k0, int bi) {
#pragma unroll
    for (int i = 0; i < 4; ++i) {
      int c = tid + i * 256;                // linear dest chunk (16B)
      int r = c >> 3;
      int u = (c & 7) ^ (r & 7);            // pre-swizzled source unit
      gl_lds16(&A[(size_t)(m0 + r) * Hv + k0 + u * 8], &sm.g.A[bi][c * 8]);
      gl_lds16(&Wt[(size_t)(n0 + r) * Hv + k0 + u * 8], &sm.g.B[bi][c * 8]);
    }
  };

  f32x4 acc[4][4] = {};

  auto KSTEP = [&](int kt) {
    const int buf = kt & 1;
#pragma unroll
    for (int kk = 0; kk < 64; kk += 32) {
      s16x8 af[4], bf[4];
#pragma unroll
      for (int m = 0; m < 4; ++m) {
        int row = wr * 64 + m * 16 + (l & 15);
        int sb = (row * 128 + kk * 2 + ((l >> 4) << 4)) ^ ((row & 7) << 4);
        af[m] = *(s16x8*)((char*)sm.g.A[buf] + sb);
      }
#pragma unroll
      for (int n = 0; n < 4; ++n) {
        int row = wc * 64 + n * 16 + (l & 15);
        int sb = (row * 128 + kk * 2 + ((l >> 4) << 4)) ^ ((row & 7) << 4);
        bf[n] = *(s16x8*)((char*)sm.g.B[buf] + sb);
      }
#pragma unroll
      for (int m = 0; m < 4; ++m)
#pragma unroll
        for (int n = 0; n < 4; ++n)
          acc[m][n] = __builtin_amdgcn_mfma_f32_16x16x32_bf16(af[m], bf[n], acc[m][n], 0, 0, 0);
    }
  };

  // prologue: stage tiles 0 and 1 (16 loads in flight)
  STAGE(0, 0);
  STAGE(64, 1);

  for (int kt = 0; kt < 15; ++kt) {
    asm volatile("s_waitcnt vmcnt(8)" ::: "memory");   // tile kt landed
    __builtin_amdgcn_s_barrier();                      // all waves' chunks in
    __builtin_amdgcn_sched_barrier(0);
    KSTEP(kt);
    __builtin_amdgcn_s_barrier();                      // all waves done reading
    __builtin_amdgcn_sched_barrier(0);
    if (kt + 2 < 16) STAGE((kt + 2) * 64, kt & 1);     // restage freed buffer
  }
  asm volatile("s_waitcnt vmcnt(0)" ::: "memory");     // tail: drain tile 15
  __builtin_amdgcn_s_barrier();
  __builtin_amdgcn_sched_barrier(0);
  KSTEP(15);
  __syncthreads();   // full barrier before epilogue union reuse

  // ---- epilogue: stage C-tile in LDS, then coalesced 16B stores ----
  const int b = m0 >> 11, s0 = m0 & (Sv - 1);
  if (sel < 2) {
    const float scale = (sel == 0) ? 0.1803368801f : 1.0f;  // log2e/8 for Q
    const float* bias = (sel == 0) ? Wqb : (Wkvb + (n0 - 1024));
#pragma unroll
    for (int m = 0; m < 4; ++m)
#pragma unroll
      for (int n = 0; n < 4; ++n) {
        int scol = wc * 64 + n * 16 + (l & 15);
#pragma unroll
        for (int e = 0; e < 4; ++e) {
          int srow = wr * 64 + m * 16 + ((l >> 4) << 2) + e;
          float v = (acc[m][n][e] + bias[scol]) * scale;
          sm.ep[srow * 136 + scol] = f2bf(v);
        }
      }
    __syncthreads();
    short* dst = sel ? Kb : Qb;
    const int hbase = (n0 & 1023) >> 6;
#pragma unroll
    for (int p = 0; p < 8; ++p) {
      int u = p * 256 + tid;                 // 2048 16B-units
      int row = u >> 4, hf = (u >> 3) & 1, sub = u & 7;
      s16x8 vdat = *(s16x8*)&sm.ep[row * 136 + hf * 64 + sub * 8];
      *(s16x8*)&dst[(((size_t)(b * NHv + hbase + hf)) * Sv + s0 + row) * HDv + sub * 8] = vdat;
    }
  } else {
    const float* bias = Wkvb + (n0 - 1024);  // V bias offset within Wkvb
#pragma unroll
    for (int m = 0; m < 4; ++m)
#pragma unroll
      for (int n = 0; n < 4; ++n) {
        int scol = wc * 64 + n * 16 + (l & 15);
        int srow0 = wr * 64 + m * 16 + ((l >> 4) << 2);
        s16x4 t;
#pragma unroll
        for (int e = 0; e < 4; ++e) t[e] = f2bf(acc[m][n][e] + bias[scol]);
        *(s16x4*)&sm.ep[scol * 136 + srow0] = t;   // transposed [col][row]
      }
    __syncthreads();
    const int hbase = (n0 - 2048) >> 6;
#pragma unroll
    for (int p = 0; p < 8; ++p) {
      int u = p * 256 + tid;                 // 2048 16B-units
      int col = u >> 4, seg = u & 15;
      s16x8 vdat = *(s16x8*)&sm.ep[col * 136 + seg * 8];
      *(s16x8*)&Vt[(((size_t)(b * NHv + hbase + (col >> 6))) * HDv + (col & 63)) * Sv + s0 + seg * 8] = vdat;
    }
  }
}

// ---------------- output projection GEMM (fp32 out) ------------------------
// Counted-vmcnt ping-pong (R26: ~20 -> ~17us, kept).
__global__ __launch_bounds__(256)
void gemm_out(const short* __restrict__ A, const short* __restrict__ Bt,
              const float* __restrict__ bias, float* __restrict__ outf) {
  __shared__ short Alds[2][128 * 64];
  __shared__ short Blds[2][128 * 64];
  const int tid = threadIdx.x;
  const int w = tid >> 6, l = tid & 63;
  const int wr = w >> 1, wc = w & 1;
  const int m0 = blockIdx.x * 128, n0 = blockIdx.y * 128;

  auto STAGE = [&](int k0, int bi) {
#pragma unroll
    for (int i = 0; i < 4; ++i) {
      int c = tid + i * 256;
      int r = c >> 3;
      int u = (c & 7) ^ (r & 7);
      gl_lds16(&A[(size_t)(m0 + r) * Hv + k0 + u * 8], &Alds[bi][c * 8]);
      gl_lds16(&Bt[(size_t)(n0 + r) * Hv + k0 + u * 8], &Blds[bi][c * 8]);
    }
  };

  f32x4 acc[4][4] = {};

  auto KSTEP = [&](int kt) {
    const int buf = kt & 1;
#pragma unroll
    for (int kk = 0; kk < 64; kk += 32) {
      s16x8 af[4], bf[4];
#pragma unroll
      for (int m = 0; m < 4; ++m) {
        int row = wr * 64 + m * 16 + (l & 15);
        int sb = (row * 128 + kk * 2 + ((l >> 4) << 4)) ^ ((row & 7) << 4);
        af[m] = *(s16x8*)((char*)Alds[buf] + sb);
      }
#pragma unroll
      for (int n = 0; n < 4; ++n) {
        int row = wc * 64 + n * 16 + (l & 15);
        int sb = (row * 128 + kk * 2 + ((l >> 4) << 4)) ^ ((row & 7) << 4);
        bf[n] = *(s16x8*)((char*)Blds[buf] + sb);
      }
#pragma unroll
      for (int m = 0; m < 4; ++m)
#pragma unroll
        for (int n = 0; n < 4; ++n)
          acc[m][n] = __builtin_amdgcn_mfma_f32_16x16x32_bf16(af[m], bf[n], acc[m][n], 0, 0, 0);
    }
  };

  STAGE(0, 0);
  STAGE(64, 1);

  for (int kt = 0; kt < 15; ++kt) {
    asm volatile("s_waitcnt vmcnt(8)" ::: "memory");
    __builtin_amdgcn_s_barrier();
    __builtin_amdgcn_sched_barrier(0);
    KSTEP(kt);
    __builtin_amdgcn_s_barrier();
    __builtin_amdgcn_sched_barrier(0);
    if (kt + 2 < 16) STAGE((kt + 2) * 64, kt & 1);
  }
  asm volatile("s_waitcnt vmcnt(0)" ::: "memory");
  __builtin_amdgcn_s_barrier();
  __builtin_amdgcn_sched_barrier(0);
  KSTEP(15);

#pragma unroll
  for (int m = 0; m < 4; ++m)
#pragma unroll
    for (int n = 0; n < 4; ++n)
#pragma unroll
      for (int e = 0; e < 4; ++e) {
        int gr = m0 + wr * 64 + m * 16 + ((l >> 4) << 2) + e;
        int gc = n0 + wc * 64 + n * 16 + (l & 15);
        outf[(size_t)gr * Hv + gc] = acc[m][n][e] + bias[gc];
      }
}

// ---------------- MFMA flash attention: 8 waves x 32 q-rows ----------------
// R25 structure + HALVED P BUFFER: the kk-half interleave has only one
// 32-k half of P live at a time, so P shrinks [32][128B] -> [32][64B]
// (2KB/wave; kk=1 overwrites kk=0's bytes after its read — per-wave
// in-order LDS ops make the WAR safe). Block LDS 64.5 -> 48.1KB ->
// 3 blocks/CU (24 waves, was 16). Swizzle reworked for 64B rows:
// (il&3)<<4; 16B pf read spans chunks differing only in bit 3, so both
// get the same XOR -> contiguous. launch_bounds(512,6) pins VGPR<=85.
__global__ __launch_bounds__(512, 6)
void attn_mfma(const short* __restrict__ Q, const short* __restrict__ Kb,
               const short* __restrict__ Vt, const unsigned char* __restrict__ msk,
               short* __restrict__ AO) {
  __shared__ short Klds[2][64 * 64];     // [k][d], swizzled
  __shared__ short Vlds[2][64 * 64];     // [d][k], swizzled
  __shared__ short Plds[8 * 32 * 32];    // per-wave [q][32k half], swizzled
  __shared__ unsigned long long mword[2];

  const int tid = threadIdx.x;
  const int w = tid >> 6, l = tid & 63;
  const int il = l & 15, g = l >> 4;
  const int bh = blockIdx.x & 63;
  const int qb = 7 - (blockIdx.x >> 6);      // heavy q-blocks first (8 blocks)
  const int b = bh >> 4, h = bh & 15;
  const int q0 = qb * 256 + w * 32;          // wave's first q row

  // hoisted loop-invariant LDS byte-offsets
  int kvA0[4], pfA0[2];
#pragma unroll
  for (int n = 0; n < 4; ++n) {
    int row = n * 16 + il;
    kvA0[n] = row * 128 + ((g << 4) ^ ((row & 7) << 4));
  }
  const int swzq = (il & 3) << 4;            // P swizzle (64B rows: bits 4-5)
  const int g8 = g << 3;
#pragma unroll
  for (int m = 0; m < 2; ++m)
    pfA0[m] = (m * 16 + il) * 64 + ((g << 4) ^ swzq);

  // Q fragments in registers (pre-scaled by log2e/8)
  s16x8 qf[2][2];
  const short* qbase = &Q[((size_t)bh * Sv + q0) * HDv];
#pragma unroll
  for (int m = 0; m < 2; ++m)
#pragma unroll
    for (int kk = 0; kk < 2; ++kk)
      qf[m][kk] = *(const s16x8*)&qbase[(m * 16 + il) * 64 + kk * 32 + g8];

  s16x8 onesf;
#pragma unroll
  for (int e2 = 0; e2 < 8; ++e2) onesf[e2] = (short)0x3F80;   // bf16 1.0

  f32x4 oacc[2][4] = {};
  f32x4 lacc[2] = {};            // row sums via ones-MFMA
  const f32x4 cinit = {-16.f, -16.f, -16.f, -16.f};   // fixed softmax shift

  char* const pbase = (char*)Plds + w * 2048;
  const short* kg0 = &Kb[(size_t)bh * Sv * HDv];
  const short* vg0 = &Vt[(size_t)bh * HDv * Sv];
  const int nkt = qb * 4 + 4;

  auto stageKV = [&](int t, int bufi) {
    const short* kg = kg0 + (size_t)t * 64 * HDv;
    const short* vg = vg0 + t * 64;
    // 512 threads: exactly one 16B chunk of K and one of V each
    int c = tid;
    int r = c >> 3;
    int u = (c & 7) ^ (r & 7);                // pre-swizzled source (involution)
    gl_lds16(&kg[(size_t)r * HDv + u * 8], &Klds[bufi][c * 8]);
    gl_lds16(&vg[(size_t)r * Sv + u * 8], &Vlds[bufi][c * 8]);
  };

  // prologue: stage tile 0
  stageKV(0, 0);
  if (w == 0) {
    unsigned long long mwb = __ballot(msk[b * Sv + l] != 0);
    if (l == 0) mword[0] = mwb;
  }
  __syncthreads();

  for (int kt = 0; kt < nkt; ++kt) {
    const int k0 = kt * 64;
    const int buf = kt & 1;
    // ---- prefetch tile kt+1 into the other buffer ----
    if (kt + 1 < nkt) {
      stageKV(kt + 1, buf ^ 1);
      if (w == 0) {
        unsigned long long mwb = __ballot(msk[b * Sv + (kt + 1) * 64 + l] != 0);
        if (l == 0) mword[buf ^ 1] = mwb;
      }
    }

    if (k0 <= q0 + 31) {   // wave has at least one valid row in this tile
      const unsigned long long mw = mword[buf];
      const char* kldsb = (const char*)Klds[buf];
      const char* vldsb = (const char*)Vlds[buf];
      // ---- QK^T, swapped operands: sacc[ktile][qtile] = S^T - 16 ----
      // C element (lane l, reg e): k = ktile*16 + 4*(l>>4)+e, q = qtile*16 + (l&15)
      f32x4 sacc[4][2];
#pragma unroll
      for (int n = 0; n < 4; ++n)
#pragma unroll
        for (int m = 0; m < 2; ++m)
          sacc[n][m] = cinit;
      __builtin_amdgcn_s_setprio(1);
#pragma unroll
      for (int kk = 0; kk < 2; ++kk) {
        s16x8 kf[4];
#pragma unroll
        for (int n = 0; n < 4; ++n)
          kf[n] = *(s16x8*)(kldsb + (kvA0[n] ^ (kk << 6)));
#pragma unroll
        for (int n = 0; n < 4; ++n)
#pragma unroll
          for (int m = 0; m < 2; ++m)
            sacc[n][m] = __builtin_amdgcn_mfma_f32_16x16x32_bf16(kf[n], qf[m][kk], sacc[n][m], 0, 0, 0);
      }
      __builtin_amdgcn_s_setprio(0);

      // ---- mask only where needed ----
      if ((k0 + 63 > q0) || (mw != 0)) {
#pragma unroll
        for (int n = 0; n < 4; ++n)
#pragma unroll
          for (int m = 0; m < 2; ++m)
#pragma unroll
            for (int e = 0; e < 4; ++e) {
              int klocal = n * 16 + (g << 2) + e;
              int qg = q0 + m * 16 + il;
              bool bad = (k0 + klocal > qg) || ((mw >> klocal) & 1ull);
              if (bad) sacc[n][m][e] = -1e30f;
            }
      }

      // ---- P halves (packed b64 writes, half-buffer reused) + PV ----
      // P = exp2(s - 16) directly; fully-masked entries -> exp2(-1e30)=0.
#pragma unroll
      for (int kk = 0; kk < 2; ++kk) {
#pragma unroll
        for (int m = 0; m < 2; ++m) {
          int pwb = (m * 16 + il) * 64;    // q-row base (64B rows)
#pragma unroll
          for (int n = kk * 2; n < kk * 2 + 2; ++n) {
            s16x4 t;
#pragma unroll
            for (int e = 0; e < 4; ++e) {
              float pv = EXP2(sacc[n][m][e]);
              t[e] = (short)(__float_as_uint(pv) >> 16);
            }
            // byte col = ((n&1)*32 + g*8) ^ swizzle, 8B-aligned
            *(s16x4*)(pbase + pwb + ((((n & 1) << 5) + g8) ^ swzq)) = t;
          }
        }
        // PV on this half
        s16x8 pf[2], vf[4];
#pragma unroll
        for (int m = 0; m < 2; ++m)
          pf[m] = *(s16x8*)(pbase + pfA0[m]);
#pragma unroll
        for (int n = 0; n < 4; ++n)
          vf[n] = *(s16x8*)(vldsb + (kvA0[n] ^ (kk << 6)));
        __builtin_amdgcn_s_setprio(1);
#pragma unroll
        for (int m = 0; m < 2; ++m) {
#pragma unroll
          for (int n = 0; n < 4; ++n)
            oacc[m][n] = __builtin_amdgcn_mfma_f32_16x16x32_bf16(pf[m], vf[n], oacc[m][n], 0, 0, 0);
          lacc[m] = __builtin_amdgcn_mfma_f32_16x16x32_bf16(pf[m], onesf, lacc[m], 0, 0, 0);
        }
        __builtin_amdgcn_s_setprio(0);
      }
    }
    __syncthreads();   // stage(kt+1) drained; all waves done with buf
  }

  // ---- epilogue: O /= rowsum, write AO [B,S,H] (bf16) ----
#pragma unroll
  for (int m = 0; m < 2; ++m)
#pragma unroll
    for (int e = 0; e < 4; ++e) {
      float inv = 1.f / lacc[m][e];
#pragma unroll
      for (int n = 0; n < 4; ++n) {
        int qg = q0 + m * 16 + (g << 2) + e;
        int dcol = n * 16 + il;
        AO[((size_t)b * Sv + qg) * Hv + h * HDv + dcol] = f2bf(oacc[m][n][e] * inv);
      }
    }
}

// ---------------------------------------------------------------------------
extern "C" void kernel_launch(void* const* d_in, const int* in_sizes, int n_in,
                              void* d_out, int out_size, void* d_ws, size_t ws_size,
                              hipStream_t stream) {
  (void)in_sizes; (void)n_in; (void)out_size; (void)ws_size;
  const float* x    = (const float*)d_in[0];
  const float* y    = (const float*)d_in[1];
  const unsigned char* msk = (const unsigned char*)d_in[2];
  const float* Wq   = (const float*)d_in[3];
  const float* Wqb  = (const float*)d_in[4];
  const float* Wkv  = (const float*)d_in[5];
  const float* Wkvb = (const float*)d_in[6];
  const float* Wo   = (const float*)d_in[7];
  const float* Wob  = (const float*)d_in[8];
  float* out = (float*)d_out;

  char* p = (char*)d_ws;
  auto alloc = [&](size_t bytes) {
    char* r = p;
    p += (bytes + 255) & ~(size_t)255;
    return r;
  };
  const size_t MT = (size_t)Bv * Sv;  // 8192
  short* Xb   = (short*)alloc(MT * Hv * 2);
  short* Yb   = (short*)alloc(MT * Hv * 2);
  short* Wt   = (short*)alloc((size_t)3 * Hv * Hv * 2);   // [Wq^T | Wkv^T] rows 0-3071
  short* Wot  = (short*)alloc((size_t)Hv * Hv * 2);
  short* Qb   = (short*)alloc(MT * Hv * 2);
  short* Kb   = (short*)alloc(MT * Hv * 2);
  short* Vb   = (short*)alloc(MT * Hv * 2);   // V^T [bh][d][s]
  short* AO   = (short*)alloc(MT * Hv * 2);

  const int n_x = (int)(MT * Hv);  // 8388608
  cvt2_bf16<<<2 * (n_x / 1024), 256, 0, stream>>>(x, y, Xb, Yb, n_x);
  tcvt3<<<dim3(128, 32), 256, 0, stream>>>(Wq, Wkv, Wo, Wt, Wot);

  gemm_qkv<<<dim3(64, 24), 256, 0, stream>>>(Xb, Yb, Wt, Wqb, Wkvb, Qb, Kb, Vb);

  attn_mfma<<<8 * 64, 512, 0, stream>>>(Qb, Kb, Vb, msk, AO);

  gemm_out<<<dim3(64, 8), 256, 0, stream>>>(AO, Wot, Wob, out);
}

// Round 29
// 155.776 us; speedup vs baseline: 2.5965x; 2.5965x over previous
//
#include <hip/hip_runtime.h>

// ---------------------------------------------------------------------------
// CrossAttention: out = (softmax_causal_masked((xWq)(yWkv_k)^T/8) (yWkv_v)) Wo
// B=4, S=2048, H=1024, NH=16, HD=64
// ---------------------------------------------------------------------------

#define Bv   4
#define Sv   2048
#define Hv   1024
#define NHv  16
#define HDv  64

typedef __attribute__((ext_vector_type(8))) short s16x8;
typedef __attribute__((ext_vector_type(4))) short s16x4;
typedef __attribute__((ext_vector_type(4))) float f32x4;

__device__ __forceinline__ short f2bf(float f) {   // RNE
  unsigned u = __float_as_uint(f);
  unsigned r = (u + 0x7fffu + ((u >> 16) & 1u)) >> 16;
  return (short)r;
}

#if __has_builtin(__builtin_amdgcn_exp2f)
#define EXP2(x) __builtin_amdgcn_exp2f(x)
#else
#define EXP2(x) exp2f(x)
#endif

// async global->LDS, 16B per lane (dest = wave-uniform base + lane*16)
__device__ __forceinline__ void gl_lds16(const short* g, short* l) {
  __builtin_amdgcn_global_load_lds(
      (const __attribute__((address_space(1))) unsigned int*)g,
      (__attribute__((address_space(3))) unsigned int*)l, 16, 0, 0);
}

// ---------------- fp32 -> bf16 convert (x and y in one launch) -------------
__global__ __launch_bounds__(256) void cvt2_bf16(const float* __restrict__ x,
                                                 const float* __restrict__ y,
                                                 short* __restrict__ Xb,
                                                 short* __restrict__ Yb, int nper) {
  int half = gridDim.x >> 1;
  int bid = blockIdx.x;
  const float* in = (bid < half) ? x : y;
  short* out = (bid < half) ? Xb : Yb;
  int lb = (bid < half) ? bid : bid - half;
  int i = (lb * 256 + threadIdx.x) * 4;
  if (i < nper) {
    float4 v = *(const float4*)&in[i];
    short r0 = f2bf(v.x), r1 = f2bf(v.y), r2 = f2bf(v.z), r3 = f2bf(v.w);
    unsigned long long pk = (unsigned long long)(unsigned short)r0
                          | ((unsigned long long)(unsigned short)r1 << 16)
                          | ((unsigned long long)(unsigned short)r2 << 32)
                          | ((unsigned long long)(unsigned short)r3 << 48);
    *(unsigned long long*)&out[i] = pk;
  }
}

// ---------------- all three weights: fp32 [R][C] -> bf16 [C][R] ------------
__global__ __launch_bounds__(256)
void tcvt3(const float* __restrict__ Wq, const float* __restrict__ Wkv,
           const float* __restrict__ Wo, short* __restrict__ Wt,
           short* __restrict__ Wot) {
  __shared__ float tile[32][33];
  int bx = blockIdx.x;
  const float* in;
  short* out;
  int C, cx;
  if (bx < 32)       { in = Wq;  out = Wt;                          C = 1024; cx = bx; }
  else if (bx < 96)  { in = Wkv; out = Wt + (size_t)Hv * Hv;        C = 2048; cx = bx - 32; }
  else               { in = Wo;  out = Wot;                         C = 1024; cx = bx - 96; }
  const int R = 1024;
  int tx = threadIdx.x & 31, ty = threadIdx.x >> 5;  // ty 0..7
  int c0 = cx * 32, r0 = blockIdx.y * 32;
#pragma unroll
  for (int i = 0; i < 32; i += 8)
    tile[ty + i][tx] = in[(size_t)(r0 + ty + i) * C + c0 + tx];
  __syncthreads();
#pragma unroll
  for (int i = 0; i < 32; i += 8)
    out[(size_t)(c0 + ty + i) * R + r0 + tx] = f2bf(tile[tx][ty + i]);
}

// ---------------- fused QKV projection GEMM --------------------------------
// Counted-vmcnt ping-pong (R23: 846 TF). LDS-staged epilogue.
__global__ __launch_bounds__(256)
void gemm_qkv(const short* __restrict__ Xb, const short* __restrict__ Yb,
              const short* __restrict__ Wt, const float* __restrict__ Wqb,
              const float* __restrict__ Wkvb, short* __restrict__ Qb,
              short* __restrict__ Kb, short* __restrict__ Vt) {
  __shared__ union SMem {
    struct { short A[2][128 * 64]; short B[2][128 * 64]; } g;
    short ep[128 * 136];                    // epilogue staging (pad 136)
  } sm;
  const int tid = threadIdx.x;
  const int w = tid >> 6, l = tid & 63;
  const int wr = w >> 1, wc = w & 1;
  const int m0 = blockIdx.x * 128, n0 = blockIdx.y * 128;
  const short* A = (n0 < 1024) ? Xb : Yb;
  const int sel = n0 >> 10;                 // 0=Q, 1=K, 2=V (blocks are pure)

  auto STAGE = [&](int k0, int bi) {
#pragma unroll
    for (int i = 0; i < 4; ++i) {
      int c = tid + i * 256;                // linear dest chunk (16B)
      int r = c >> 3;
      int u = (c & 7) ^ (r & 7);            // pre-swizzled source unit
      gl_lds16(&A[(size_t)(m0 + r) * Hv + k0 + u * 8], &sm.g.A[bi][c * 8]);
      gl_lds16(&Wt[(size_t)(n0 + r) * Hv + k0 + u * 8], &sm.g.B[bi][c * 8]);
    }
  };

  f32x4 acc[4][4] = {};

  auto KSTEP = [&](int kt) {
    const int buf = kt & 1;
#pragma unroll
    for (int kk = 0; kk < 64; kk += 32) {
      s16x8 af[4], bf[4];
#pragma unroll
      for (int m = 0; m < 4; ++m) {
        int row = wr * 64 + m * 16 + (l & 15);
        int sb = (row * 128 + kk * 2 + ((l >> 4) << 4)) ^ ((row & 7) << 4);
        af[m] = *(s16x8*)((char*)sm.g.A[buf] + sb);
      }
#pragma unroll
      for (int n = 0; n < 4; ++n) {
        int row = wc * 64 + n * 16 + (l & 15);
        int sb = (row * 128 + kk * 2 + ((l >> 4) << 4)) ^ ((row & 7) << 4);
        bf[n] = *(s16x8*)((char*)sm.g.B[buf] + sb);
      }
#pragma unroll
      for (int m = 0; m < 4; ++m)
#pragma unroll
        for (int n = 0; n < 4; ++n)
          acc[m][n] = __builtin_amdgcn_mfma_f32_16x16x32_bf16(af[m], bf[n], acc[m][n], 0, 0, 0);
    }
  };

  // prologue: stage tiles 0 and 1 (16 loads in flight)
  STAGE(0, 0);
  STAGE(64, 1);

  for (int kt = 0; kt < 15; ++kt) {
    asm volatile("s_waitcnt vmcnt(8)" ::: "memory");   // tile kt landed
    __builtin_amdgcn_s_barrier();                      // all waves' chunks in
    __builtin_amdgcn_sched_barrier(0);
    KSTEP(kt);
    __builtin_amdgcn_s_barrier();                      // all waves done reading
    __builtin_amdgcn_sched_barrier(0);
    if (kt + 2 < 16) STAGE((kt + 2) * 64, kt & 1);     // restage freed buffer
  }
  asm volatile("s_waitcnt vmcnt(0)" ::: "memory");     // tail: drain tile 15
  __builtin_amdgcn_s_barrier();
  __builtin_amdgcn_sched_barrier(0);
  KSTEP(15);
  __syncthreads();   // full barrier before epilogue union reuse

  // ---- epilogue: stage C-tile in LDS, then coalesced 16B stores ----
  const int b = m0 >> 11, s0 = m0 & (Sv - 1);
  if (sel < 2) {
    const float scale = (sel == 0) ? 0.1803368801f : 1.0f;  // log2e/8 for Q
    const float* bias = (sel == 0) ? Wqb : (Wkvb + (n0 - 1024));
#pragma unroll
    for (int m = 0; m < 4; ++m)
#pragma unroll
      for (int n = 0; n < 4; ++n) {
        int scol = wc * 64 + n * 16 + (l & 15);
#pragma unroll
        for (int e = 0; e < 4; ++e) {
          int srow = wr * 64 + m * 16 + ((l >> 4) << 2) + e;
          float v = (acc[m][n][e] + bias[scol]) * scale;
          sm.ep[srow * 136 + scol] = f2bf(v);
        }
      }
    __syncthreads();
    short* dst = sel ? Kb : Qb;
    const int hbase = (n0 & 1023) >> 6;
#pragma unroll
    for (int p = 0; p < 8; ++p) {
      int u = p * 256 + tid;                 // 2048 16B-units
      int row = u >> 4, hf = (u >> 3) & 1, sub = u & 7;
      s16x8 vdat = *(s16x8*)&sm.ep[row * 136 + hf * 64 + sub * 8];
      *(s16x8*)&dst[(((size_t)(b * NHv + hbase + hf)) * Sv + s0 + row) * HDv + sub * 8] = vdat;
    }
  } else {
    const float* bias = Wkvb + (n0 - 1024);  // V bias offset within Wkvb
#pragma unroll
    for (int m = 0; m < 4; ++m)
#pragma unroll
      for (int n = 0; n < 4; ++n) {
        int scol = wc * 64 + n * 16 + (l & 15);
        int srow0 = wr * 64 + m * 16 + ((l >> 4) << 2);
        s16x4 t;
#pragma unroll
        for (int e = 0; e < 4; ++e) t[e] = f2bf(acc[m][n][e] + bias[scol]);
        *(s16x4*)&sm.ep[scol * 136 + srow0] = t;   // transposed [col][row]
      }
    __syncthreads();
    const int hbase = (n0 - 2048) >> 6;
#pragma unroll
    for (int p = 0; p < 8; ++p) {
      int u = p * 256 + tid;                 // 2048 16B-units
      int col = u >> 4, seg = u & 15;
      s16x8 vdat = *(s16x8*)&sm.ep[col * 136 + seg * 8];
      *(s16x8*)&Vt[(((size_t)(b * NHv + hbase + (col >> 6))) * HDv + (col & 63)) * Sv + s0 + seg * 8] = vdat;
    }
  }
}

// ---------------- output projection GEMM (fp32 out) ------------------------
// Counted-vmcnt ping-pong (R26: ~20 -> ~17us, kept).
__global__ __launch_bounds__(256)
void gemm_out(const short* __restrict__ A, const short* __restrict__ Bt,
              const float* __restrict__ bias, float* __restrict__ outf) {
  __shared__ short Alds[2][128 * 64];
  __shared__ short Blds[2][128 * 64];
  const int tid = threadIdx.x;
  const int w = tid >> 6, l = tid & 63;
  const int wr = w >> 1, wc = w & 1;
  const int m0 = blockIdx.x * 128, n0 = blockIdx.y * 128;

  auto STAGE = [&](int k0, int bi) {
#pragma unroll
    for (int i = 0; i < 4; ++i) {
      int c = tid + i * 256;
      int r = c >> 3;
      int u = (c & 7) ^ (r & 7);
      gl_lds16(&A[(size_t)(m0 + r) * Hv + k0 + u * 8], &Alds[bi][c * 8]);
      gl_lds16(&Bt[(size_t)(n0 + r) * Hv + k0 + u * 8], &Blds[bi][c * 8]);
    }
  };

  f32x4 acc[4][4] = {};

  auto KSTEP = [&](int kt) {
    const int buf = kt & 1;
#pragma unroll
    for (int kk = 0; kk < 64; kk += 32) {
      s16x8 af[4], bf[4];
#pragma unroll
      for (int m = 0; m < 4; ++m) {
        int row = wr * 64 + m * 16 + (l & 15);
        int sb = (row * 128 + kk * 2 + ((l >> 4) << 4)) ^ ((row & 7) << 4);
        af[m] = *(s16x8*)((char*)Alds[buf] + sb);
      }
#pragma unroll
      for (int n = 0; n < 4; ++n) {
        int row = wc * 64 + n * 16 + (l & 15);
        int sb = (row * 128 + kk * 2 + ((l >> 4) << 4)) ^ ((row & 7) << 4);
        bf[n] = *(s16x8*)((char*)Blds[buf] + sb);
      }
#pragma unroll
      for (int m = 0; m < 4; ++m)
#pragma unroll
        for (int n = 0; n < 4; ++n)
          acc[m][n] = __builtin_amdgcn_mfma_f32_16x16x32_bf16(af[m], bf[n], acc[m][n], 0, 0, 0);
    }
  };

  STAGE(0, 0);
  STAGE(64, 1);

  for (int kt = 0; kt < 15; ++kt) {
    asm volatile("s_waitcnt vmcnt(8)" ::: "memory");
    __builtin_amdgcn_s_barrier();
    __builtin_amdgcn_sched_barrier(0);
    KSTEP(kt);
    __builtin_amdgcn_s_barrier();
    __builtin_amdgcn_sched_barrier(0);
    if (kt + 2 < 16) STAGE((kt + 2) * 64, kt & 1);
  }
  asm volatile("s_waitcnt vmcnt(0)" ::: "memory");
  __builtin_amdgcn_s_barrier();
  __builtin_amdgcn_sched_barrier(0);
  KSTEP(15);

#pragma unroll
  for (int m = 0; m < 4; ++m)
#pragma unroll
    for (int n = 0; n < 4; ++n)
#pragma unroll
      for (int e = 0; e < 4; ++e) {
        int gr = m0 + wr * 64 + m * 16 + ((l >> 4) << 2) + e;
        int gc = n0 + wc * 64 + n * 16 + (l & 15);
        outf[(size_t)gr * Hv + gc] = acc[m][n][e] + bias[gc];
      }
}

// ---------------- MFMA flash attention: 8 waves x 32 q-rows ----------------
// R27 anchor (155.9us total). KVBLK=64, 2-phase dbuf, heavy-first qb,
// swapped QK^T + b64 P-writes, fixed-shift softmax (exp2(s-16)).
// R28's launch_bounds(512,6) pin collapsed VGPR 84->40 -> massive spills
// (FETCH 33->420MB, attn 58->303us): never pin occupancy below natural
// allocation on a VGPR-tight kernel.
__global__ __launch_bounds__(512)
void attn_mfma(const short* __restrict__ Q, const short* __restrict__ Kb,
               const short* __restrict__ Vt, const unsigned char* __restrict__ msk,
               short* __restrict__ AO) {
  __shared__ short Klds[2][64 * 64];     // [k][d], swizzled
  __shared__ short Vlds[2][64 * 64];     // [d][k], swizzled
  __shared__ short Plds[8 * 32 * 64];    // per-wave [q][k], swizzled
  __shared__ unsigned long long mword[2];

  const int tid = threadIdx.x;
  const int w = tid >> 6, l = tid & 63;
  const int il = l & 15, g = l >> 4;
  const int bh = blockIdx.x & 63;
  const int qb = 7 - (blockIdx.x >> 6);      // heavy q-blocks first (8 blocks)
  const int b = bh >> 4, h = bh & 15;
  const int q0 = qb * 256 + w * 32;          // wave's first q row

  // hoisted loop-invariant LDS byte-offsets
  int kvA0[4], pfA0[2];
#pragma unroll
  for (int n = 0; n < 4; ++n) {
    int row = n * 16 + il;
    kvA0[n] = row * 128 + ((g << 4) ^ ((row & 7) << 4));
  }
#pragma unroll
  for (int m = 0; m < 2; ++m) {
    int row = m * 16 + il;
    pfA0[m] = row * 128 + ((g << 4) ^ ((row & 7) << 4));
  }
  const int swzq = (il & 7) << 4;            // P-write swizzle (row&7 = il&7)
  const int g8 = g << 3;

  // Q fragments in registers (pre-scaled by log2e/8)
  s16x8 qf[2][2];
  const short* qbase = &Q[((size_t)bh * Sv + q0) * HDv];
#pragma unroll
  for (int m = 0; m < 2; ++m)
#pragma unroll
    for (int kk = 0; kk < 2; ++kk)
      qf[m][kk] = *(const s16x8*)&qbase[(m * 16 + il) * 64 + kk * 32 + g8];

  s16x8 onesf;
#pragma unroll
  for (int e2 = 0; e2 < 8; ++e2) onesf[e2] = (short)0x3F80;   // bf16 1.0

  f32x4 oacc[2][4] = {};
  f32x4 lacc[2] = {};            // row sums via ones-MFMA
  const f32x4 cinit = {-16.f, -16.f, -16.f, -16.f};   // fixed softmax shift

  char* const pbase = (char*)Plds + w * 4096;
  const short* kg0 = &Kb[(size_t)bh * Sv * HDv];
  const short* vg0 = &Vt[(size_t)bh * HDv * Sv];
  const int nkt = qb * 4 + 4;

  auto stageKV = [&](int t, int bufi) {
    const short* kg = kg0 + (size_t)t * 64 * HDv;
    const short* vg = vg0 + t * 64;
    // 512 threads: exactly one 16B chunk of K and one of V each
    int c = tid;
    int r = c >> 3;
    int u = (c & 7) ^ (r & 7);                // pre-swizzled source (involution)
    gl_lds16(&kg[(size_t)r * HDv + u * 8], &Klds[bufi][c * 8]);
    gl_lds16(&vg[(size_t)r * Sv + u * 8], &Vlds[bufi][c * 8]);
  };

  // prologue: stage tile 0
  stageKV(0, 0);
  if (w == 0) {
    unsigned long long mwb = __ballot(msk[b * Sv + l] != 0);
    if (l == 0) mword[0] = mwb;
  }
  __syncthreads();

  for (int kt = 0; kt < nkt; ++kt) {
    const int k0 = kt * 64;
    const int buf = kt & 1;
    // ---- prefetch tile kt+1 into the other buffer ----
    if (kt + 1 < nkt) {
      stageKV(kt + 1, buf ^ 1);
      if (w == 0) {
        unsigned long long mwb = __ballot(msk[b * Sv + (kt + 1) * 64 + l] != 0);
        if (l == 0) mword[buf ^ 1] = mwb;
      }
    }

    if (k0 <= q0 + 31) {   // wave has at least one valid row in this tile
      const unsigned long long mw = mword[buf];
      const char* kldsb = (const char*)Klds[buf];
      const char* vldsb = (const char*)Vlds[buf];
      // ---- QK^T, swapped operands: sacc[ktile][qtile] = S^T - 16 ----
      // C element (lane l, reg e): k = ktile*16 + 4*(l>>4)+e, q = qtile*16 + (l&15)
      f32x4 sacc[4][2];
#pragma unroll
      for (int n = 0; n < 4; ++n)
#pragma unroll
        for (int m = 0; m < 2; ++m)
          sacc[n][m] = cinit;
      __builtin_amdgcn_s_setprio(1);
#pragma unroll
      for (int kk = 0; kk < 2; ++kk) {
        s16x8 kf[4];
#pragma unroll
        for (int n = 0; n < 4; ++n)
          kf[n] = *(s16x8*)(kldsb + (kvA0[n] ^ (kk << 6)));
#pragma unroll
        for (int n = 0; n < 4; ++n)
#pragma unroll
          for (int m = 0; m < 2; ++m)
            sacc[n][m] = __builtin_amdgcn_mfma_f32_16x16x32_bf16(kf[n], qf[m][kk], sacc[n][m], 0, 0, 0);
      }
      __builtin_amdgcn_s_setprio(0);

      // ---- mask only where needed ----
      if ((k0 + 63 > q0) || (mw != 0)) {
#pragma unroll
        for (int n = 0; n < 4; ++n)
#pragma unroll
          for (int m = 0; m < 2; ++m)
#pragma unroll
            for (int e = 0; e < 4; ++e) {
              int klocal = n * 16 + (g << 2) + e;
              int qg = q0 + m * 16 + il;
              bool bad = (k0 + klocal > qg) || ((mw >> klocal) & 1ull);
              if (bad) sacc[n][m][e] = -1e30f;
            }
      }

      // ---- P halves (packed b64 writes) + PV interleaved ----
      // P = exp2(s - 16) directly; fully-masked entries -> exp2(-1e30)=0.
#pragma unroll
      for (int kk = 0; kk < 2; ++kk) {
        // exp + write P for k in [kk*32, kk*32+32): ktiles 2kk, 2kk+1
#pragma unroll
        for (int m = 0; m < 2; ++m) {
          int pwb = (m * 16 + il) * 128;   // q-row base
#pragma unroll
          for (int n = kk * 2; n < kk * 2 + 2; ++n) {
            s16x4 t;
#pragma unroll
            for (int e = 0; e < 4; ++e) {
              float pv = EXP2(sacc[n][m][e]);
              t[e] = (short)(__float_as_uint(pv) >> 16);
            }
            // byte col = (ktile*32 + g*8) ^ swizzle, 8B-aligned
            *(s16x4*)(pbase + pwb + (((n << 5) + g8) ^ swzq)) = t;
          }
        }
        // PV on this half
        s16x8 pf[2], vf[4];
#pragma unroll
        for (int m = 0; m < 2; ++m)
          pf[m] = *(s16x8*)(pbase + (pfA0[m] ^ (kk << 6)));
#pragma unroll
        for (int n = 0; n < 4; ++n)
          vf[n] = *(s16x8*)(vldsb + (kvA0[n] ^ (kk << 6)));
        __builtin_amdgcn_s_setprio(1);
#pragma unroll
        for (int m = 0; m < 2; ++m) {
#pragma unroll
          for (int n = 0; n < 4; ++n)
            oacc[m][n] = __builtin_amdgcn_mfma_f32_16x16x32_bf16(pf[m], vf[n], oacc[m][n], 0, 0, 0);
          lacc[m] = __builtin_amdgcn_mfma_f32_16x16x32_bf16(pf[m], onesf, lacc[m], 0, 0, 0);
        }
        __builtin_amdgcn_s_setprio(0);
      }
    }
    __syncthreads();   // stage(kt+1) drained; all waves done with buf
  }

  // ---- epilogue: O /= rowsum, write AO [B,S,H] (bf16) ----
#pragma unroll
  for (int m = 0; m < 2; ++m)
#pragma unroll
    for (int e = 0; e < 4; ++e) {
      float inv = 1.f / lacc[m][e];
#pragma unroll
      for (int n = 0; n < 4; ++n) {
        int qg = q0 + m * 16 + (g << 2) + e;
        int dcol = n * 16 + il;
        AO[((size_t)b * Sv + qg) * Hv + h * HDv + dcol] = f2bf(oacc[m][n][e] * inv);
      }
    }
}

// ---------------------------------------------------------------------------
extern "C" void kernel_launch(void* const* d_in, const int* in_sizes, int n_in,
                              void* d_out, int out_size, void* d_ws, size_t ws_size,
                              hipStream_t stream) {
  (void)in_sizes; (void)n_in; (void)out_size; (void)ws_size;
  const float* x    = (const float*)d_in[0];
  const float* y    = (const float*)d_in[1];
  const unsigned char* msk = (const unsigned char*)d_in[2];
  const float* Wq   = (const float*)d_in[3];
  const float* Wqb  = (const float*)d_in[4];
  const float* Wkv  = (const float*)d_in[5];
  const float* Wkvb = (const float*)d_in[6];
  const float* Wo   = (const float*)d_in[7];
  const float* Wob  = (const float*)d_in[8];
  float* out = (float*)d_out;

  char* p = (char*)d_ws;
  auto alloc = [&](size_t bytes) {
    char* r = p;
    p += (bytes + 255) & ~(size_t)255;
    return r;
  };
  const size_t MT = (size_t)Bv * Sv;  // 8192
  short* Xb   = (short*)alloc(MT * Hv * 2);
  short* Yb   = (short*)alloc(MT * Hv * 2);
  short* Wt   = (short*)alloc((size_t)3 * Hv * Hv * 2);   // [Wq^T | Wkv^T] rows 0-3071
  short* Wot  = (short*)alloc((size_t)Hv * Hv * 2);
  short* Qb   = (short*)alloc(MT * Hv * 2);
  short* Kb   = (short*)alloc(MT * Hv * 2);
  short* Vb   = (short*)alloc(MT * Hv * 2);   // V^T [bh][d][s]
  short* AO   = (short*)alloc(MT * Hv * 2);

  const int n_x = (int)(MT * Hv);  // 8388608
  cvt2_bf16<<<2 * (n_x / 1024), 256, 0, stream>>>(x, y, Xb, Yb, n_x);
  tcvt3<<<dim3(128, 32), 256, 0, stream>>>(Wq, Wkv, Wo, Wt, Wot);

  gemm_qkv<<<dim3(64, 24), 256, 0, stream>>>(Xb, Yb, Wt, Wqb, Wkvb, Qb, Kb, Vb);

  attn_mfma<<<8 * 64, 512, 0, stream>>>(Qb, Kb, Vb, msk, AO);

  gemm_out<<<dim3(64, 8), 256, 0, stream>>>(AO, Wot, Wob, out);
}